// Round 2
// baseline (566.801 us; speedup 1.0000x reference)
//
#include <hip/hip_runtime.h>
#include <stdint.h>

// Problem constants (B, T, V, E, U)
constexpr int NB = 1024;
constexpr int NT = 80;
constexpr int NV = 50000;
constexpr int NE = 512;
constexpr int NU = 512;

typedef __attribute__((ext_vector_type(8))) __bf16 bf16x8;
typedef __attribute__((ext_vector_type(4))) float f32x4;
typedef __attribute__((ext_vector_type(4))) uint16_t u16x4;
typedef __attribute__((ext_vector_type(4))) float float4v;
typedef __attribute__((ext_vector_type(4))) uint32_t u32x4;

__device__ __forceinline__ uint16_t f2bf(float f) {
  uint32_t u = __builtin_bit_cast(uint32_t, f);
  u += 0x7FFFu + ((u >> 16) & 1u);   // round-to-nearest-even
  return (uint16_t)(u >> 16);
}
__device__ __forceinline__ float bf2f(uint16_t h) {
  uint32_t u = ((uint32_t)h) << 16;
  return __builtin_bit_cast(float, u);
}
__device__ __forceinline__ float tanh_fast(float x) {
  float e = __expf(2.0f * x);
  return 1.0f - 2.0f / (e + 1.0f);
}

// ---------------- prep kernels (unchanged) ----------------

__global__ __launch_bounds__(256) void emb_to_bf16(const float* __restrict__ in,
                                                   uint16_t* __restrict__ out) {
  int i = blockIdx.x * 256 + threadIdx.x;           // 6,400,000 float4s
  float4v v = ((const float4v*)in)[i];
  u16x4 o;
  o.x = f2bf(v.x); o.y = f2bf(v.y); o.z = f2bf(v.z); o.w = f2bf(v.w);
  ((u16x4*)out)[i] = o;
}

// Pack a [K=512][N=512] fp32 weight into MFMA-B-fragment order:
// pack[nt][ks][lane][j] = bf16( W[ks*32 + (lane>>4)*8 + j][nt*16 + (lane&15)] )
__global__ __launch_bounds__(256) void pack_w(const float* __restrict__ w,
                                              uint16_t* __restrict__ out) {
  int idx = blockIdx.x * 256 + threadIdx.x;  // 0..32767 = 32 nt * 16 ks * 64 lanes
  int lane = idx & 63;
  int ks = (idx >> 6) & 15;
  int nt = idx >> 10;
  int n  = nt * 16 + (lane & 15);
  int k0 = ks * 32 + (lane >> 4) * 8;
  uint16_t v[8];
#pragma unroll
  for (int j = 0; j < 8; j++) v[j] = f2bf(w[(size_t)(k0 + j) * NU + n]);
  u16x4* o = (u16x4*)(out + (size_t)idx * 8);
  o[0] = (u16x4){v[0], v[1], v[2], v[3]};
  o[1] = (u16x4){v[4], v[5], v[6], v[7]};
}

// ---------------- projection GEMM (unchanged) -------
__global__ __launch_bounds__(256, 2) void proj_gemm(const int* __restrict__ tokens,
                                                    const uint16_t* __restrict__ embb,
                                                    const uint16_t* __restrict__ kpack,
                                                    const float* __restrict__ bias,
                                                    uint16_t* __restrict__ xkp) {
  int wave = threadIdx.x >> 6;
  int lane = threadIdx.x & 63;
  int ln15 = lane & 15;
  int quad = lane >> 4;
  int m0 = blockIdx.x * 64;      // 1280 blocks: 80 t x 16 b-groups
  int t = m0 >> 10;
  int b0 = m0 & 1023;

  int tok[4];
#pragma unroll
  for (int mt = 0; mt < 4; mt++)
    tok[mt] = tokens[(size_t)(b0 + mt * 16 + ln15) * NT + t];

  float bv[8];
#pragma unroll
  for (int nt = 0; nt < 8; nt++) bv[nt] = bias[wave * 128 + nt * 16 + ln15];

  f32x4 acc[4][8];
#pragma unroll
  for (int mt = 0; mt < 4; mt++)
#pragma unroll
    for (int nt = 0; nt < 8; nt++) acc[mt][nt] = (f32x4){0.f, 0.f, 0.f, 0.f};

  bf16x8 aC[4], aN[4];
#pragma unroll
  for (int mt = 0; mt < 4; mt++) {
    aC[mt] = *(const bf16x8*)(embb + (size_t)tok[mt] * NE + 0 * 32 + quad * 8);
    aN[mt] = *(const bf16x8*)(embb + (size_t)tok[mt] * NE + 1 * 32 + quad * 8);
  }

#pragma unroll 1
  for (int ks = 0; ks < 16; ks++) {
    bf16x8 aF[4];
    int ksn = (ks + 2) & 15;   // wraps harmlessly for ks=14,15
#pragma unroll
    for (int mt = 0; mt < 4; mt++)
      aF[mt] = *(const bf16x8*)(embb + (size_t)tok[mt] * NE + ksn * 32 + quad * 8);
#pragma unroll
    for (int nt = 0; nt < 8; nt++) {
      int ntg = wave * 8 + nt;
      bf16x8 bfr = *(const bf16x8*)(kpack + (((size_t)ntg * 16 + ks) * 64 + lane) * 8);
#pragma unroll
      for (int mt = 0; mt < 4; mt++)
        acc[mt][nt] = __builtin_amdgcn_mfma_f32_16x16x32_bf16(aC[mt], bfr, acc[mt][nt], 0, 0, 0);
    }
#pragma unroll
    for (int mt = 0; mt < 4; mt++) { aC[mt] = aN[mt]; aN[mt] = aF[mt]; }
  }

  // epilogue: C-fragment-order tiles, coalesced 8B/lane stores
#pragma unroll
  for (int mt = 0; mt < 4; mt++) {
    int g = (b0 >> 4) + mt;
#pragma unroll
    for (int nt = 0; nt < 8; nt++) {
      int ntg = wave * 8 + nt;
      size_t tile = ((size_t)t * 64 + g) * 32 + ntg;
      u16x4 o;
      o.x = f2bf(acc[mt][nt][0] + bv[nt]);
      o.y = f2bf(acc[mt][nt][1] + bv[nt]);
      o.z = f2bf(acc[mt][nt][2] + bv[nt]);
      o.w = f2bf(acc[mt][nt][3] + bv[nt]);
      *(u16x4*)(xkp + tile * 256 + (size_t)lane * 4) = o;
    }
  }
}

// ---------------- recurrence: fully block-local, zero exchange ------------
// 64 blocks x 512 threads (8 waves, 2/SIMD). Block g owns rows g*16..+15 and
// computes ALL 512 columns of h each step -> no inter-block communication,
// no LLC round trips, no flags; ONE __syncthreads per step (double-buffered
// LDS h-tile). Wave w owns cols w*64..+63 (4 n-tiles).
//
// R (512KB) = the CU's entire VGPR file, so it can't be fully persistent:
//  * ks 0..7  -> persistent B-frags in registers (128 VGPR/wave)
//  * ks 8..15 -> streamed from L2 every step (rpack is 512KB, L2-resident;
//    8 blocks/XCD share 4.3 TB/s -> ~0.24us/step, overlapped with MFMA).
//    Stream loads are software-pipelined in 2-ks batches; the base pointer
//    is laundered through empty asm each iteration so loop-invariant loads
//    can't be hoisted out of the t-loop (they'd spill).
// h-tile LDS layout: A-frag order [ks][row16][slot4][j8], XOR-swizzled
// slot = qw ^ ((row>>1)&3) (verified last round: conflicts 6.5M -> 12K).
__global__ __launch_bounds__(512, 2)
void rnn_rec(const uint16_t* __restrict__ xkp,
             const uint16_t* __restrict__ rpack,
             const float* __restrict__ fcw,
             const float* __restrict__ fcb,
             float* __restrict__ out) {
  __shared__ uint16_t hS[2 * 8192];   // two 16KB h-tiles

  const int g = blockIdx.x;
  const int wave = threadIdx.x >> 6, lane = threadIdx.x & 63;
  const int ln15 = lane & 15, quad = lane >> 4;
  const int ntg0 = wave * 4;                    // first owned n-tile
  const int aswz = quad ^ ((ln15 >> 1) & 3);    // swizzled 16B-slot for A-reads

  // persistent B-frags for ks 0..7 (128 VGPRs)
  bf16x8 bP[8][4];
#pragma unroll
  for (int ks = 0; ks < 8; ks++)
#pragma unroll
    for (int n = 0; n < 4; n++)
      bP[ks][n] = *(const bf16x8*)(rpack + (((size_t)(ntg0 + n) * 16 + ks) * 64 + lane) * 8);

  // h(0) = 0: zero both buffers
  {
    u32x4 z = (u32x4){0u, 0u, 0u, 0u};
#pragma unroll
    for (int i = 0; i < 4; i++) ((u32x4*)hS)[i * 512 + threadIdx.x] = z;
  }

  // prefetch xk(0)
  u16x4 xc[4];
#pragma unroll
  for (int n = 0; n < 4; n++)
    xc[n] = *(const u16x4*)(xkp + (((size_t)0 * 64 + g) * 32 + ntg0 + n) * 256 + (size_t)lane * 4);

  __syncthreads();

#pragma unroll 1
  for (int t = 0; t < NT; ++t) {
    const uint16_t* hR = hS + (t & 1) * 8192;
    uint16_t* hW = hS + ((t & 1) ^ 1) * 8192;

    // launder streaming base: defeats loop-invariant hoisting of rpack loads
    const uint16_t* rps = rpack;
    asm volatile("" : "+v"(rps));

    bf16x8 s0[2][4], s1[2][4];
    // issue stream batch 0 (ks 8,9)
#pragma unroll
    for (int k = 0; k < 2; k++)
#pragma unroll
      for (int n = 0; n < 4; n++)
        s0[k][n] = *(const bf16x8*)(rps + (((size_t)(ntg0 + n) * 16 + 8 + k) * 64 + lane) * 8);

    // prefetch xk(t+1) (HBM; lands before the tanh at step end)
    u16x4 xn[4];
    {
      int tn = (t + 1 < NT) ? t + 1 : t;
#pragma unroll
      for (int n = 0; n < 4; n++)
        xn[n] = *(const u16x4*)(xkp + (((size_t)tn * 64 + g) * 32 + ntg0 + n) * 256 + (size_t)lane * 4);
    }

    f32x4 acc[4];
#pragma unroll
    for (int n = 0; n < 4; n++) acc[n] = (f32x4){0.f, 0.f, 0.f, 0.f};

    // phase 1a: ks 0..3 (persistent B) — covers batch-0 L2 latency
#pragma unroll
    for (int ks = 0; ks < 4; ks++) {
      bf16x8 a = *(const bf16x8*)(hR + (size_t)ks * 512 + ln15 * 32 + aswz * 8);
#pragma unroll
      for (int n = 0; n < 4; n++)
        acc[n] = __builtin_amdgcn_mfma_f32_16x16x32_bf16(a, bP[ks][n], acc[n], 0, 0, 0);
    }
    // issue stream batch 1 (ks 10,11)
#pragma unroll
    for (int k = 0; k < 2; k++)
#pragma unroll
      for (int n = 0; n < 4; n++)
        s1[k][n] = *(const bf16x8*)(rps + (((size_t)(ntg0 + n) * 16 + 10 + k) * 64 + lane) * 8);
    // phase 1b: ks 4..7 (persistent B)
#pragma unroll
    for (int ks = 4; ks < 8; ks++) {
      bf16x8 a = *(const bf16x8*)(hR + (size_t)ks * 512 + ln15 * 32 + aswz * 8);
#pragma unroll
      for (int n = 0; n < 4; n++)
        acc[n] = __builtin_amdgcn_mfma_f32_16x16x32_bf16(a, bP[ks][n], acc[n], 0, 0, 0);
    }
    // phase 2a: consume ks 8,9; refill s0 with ks 12,13
#pragma unroll
    for (int k = 0; k < 2; k++) {
      bf16x8 a = *(const bf16x8*)(hR + (size_t)(8 + k) * 512 + ln15 * 32 + aswz * 8);
#pragma unroll
      for (int n = 0; n < 4; n++)
        acc[n] = __builtin_amdgcn_mfma_f32_16x16x32_bf16(a, s0[k][n], acc[n], 0, 0, 0);
    }
#pragma unroll
    for (int k = 0; k < 2; k++)
#pragma unroll
      for (int n = 0; n < 4; n++)
        s0[k][n] = *(const bf16x8*)(rps + (((size_t)(ntg0 + n) * 16 + 12 + k) * 64 + lane) * 8);
    // phase 2b: consume ks 10,11; refill s1 with ks 14,15
#pragma unroll
    for (int k = 0; k < 2; k++) {
      bf16x8 a = *(const bf16x8*)(hR + (size_t)(10 + k) * 512 + ln15 * 32 + aswz * 8);
#pragma unroll
      for (int n = 0; n < 4; n++)
        acc[n] = __builtin_amdgcn_mfma_f32_16x16x32_bf16(a, s1[k][n], acc[n], 0, 0, 0);
    }
#pragma unroll
    for (int k = 0; k < 2; k++)
#pragma unroll
      for (int n = 0; n < 4; n++)
        s1[k][n] = *(const bf16x8*)(rps + (((size_t)(ntg0 + n) * 16 + 14 + k) * 64 + lane) * 8);
    // phase 2c: consume ks 12,13
#pragma unroll
    for (int k = 0; k < 2; k++) {
      bf16x8 a = *(const bf16x8*)(hR + (size_t)(12 + k) * 512 + ln15 * 32 + aswz * 8);
#pragma unroll
      for (int n = 0; n < 4; n++)
        acc[n] = __builtin_amdgcn_mfma_f32_16x16x32_bf16(a, s0[k][n], acc[n], 0, 0, 0);
    }
    // phase 2d: consume ks 14,15
#pragma unroll
    for (int k = 0; k < 2; k++) {
      bf16x8 a = *(const bf16x8*)(hR + (size_t)(14 + k) * 512 + ln15 * 32 + aswz * 8);
#pragma unroll
      for (int n = 0; n < 4; n++)
        acc[n] = __builtin_amdgcn_mfma_f32_16x16x32_bf16(a, s1[k][n], acc[n], 0, 0, 0);
    }

    // tanh (xk was prefetched last step)
    uint16_t hv[4][4];
#pragma unroll
    for (int n = 0; n < 4; n++)
#pragma unroll
      for (int r = 0; r < 4; r++)
        hv[n][r] = f2bf(tanh_fast(acc[n][r] + bf2f(xc[n][r])));
#pragma unroll
    for (int n = 0; n < 4; n++) xc[n] = xn[n];

    // repack own 64 cols into hW (wave-local regions ks 2w, 2w+1), swizzled
#pragma unroll
    for (int n = 0; n < 4; n++) {
      int col = wave * 64 + n * 16 + ln15;
      int ksR = col >> 5;
      int qw = (col >> 3) & 3;
      int j = col & 7;
#pragma unroll
      for (int r = 0; r < 4; r++) {
        int row = quad * 4 + r;
        hW[(size_t)ksR * 512 + row * 32 + ((qw ^ ((row >> 1) & 3)) << 3) + j] = hv[n][r];
      }
    }
    __syncthreads();   // h(t+1) complete; flip buffers
  }

  // final FC + sigmoid: h(80) in buffer 0 (NT even); each wave does 2 rows
  {
    const uint16_t* hB = hS + (NT & 1) * 8192;
#pragma unroll
    for (int rr = 0; rr < 2; rr++) {
      int row = wave * 2 + rr;
      // cols lane*8..+7: ks = lane>>2, logical qw = lane&3 -> swizzled slot
      int slot = (lane & 3) ^ ((row >> 1) & 3);
      const uint16_t* hr = hB + (size_t)(lane >> 2) * 512 + row * 32 + slot * 8;
      float p = 0.f;
#pragma unroll
      for (int j = 0; j < 8; j++) p += bf2f(hr[j]) * fcw[lane * 8 + j];
#pragma unroll
      for (int off = 32; off; off >>= 1) p += __shfl_down(p, off);
      if (lane == 0) {
        float logit = p + fcb[0];
        out[g * 16 + row] = 1.0f / (1.0f + __expf(-logit));
      }
    }
  }
}

// ---------------- launcher ----------------
extern "C" void kernel_launch(void* const* d_in, const int* in_sizes, int n_in,
                              void* d_out, int out_size, void* d_ws, size_t ws_size,
                              hipStream_t stream) {
  const int* tokens   = (const int*)d_in[0];
  const float* emb    = (const float*)d_in[1];
  const float* kernel_w = (const float*)d_in[2];
  const float* rec_w  = (const float*)d_in[3];
  const float* bias   = (const float*)d_in[4];
  const float* fcw    = (const float*)d_in[5];
  const float* fcb    = (const float*)d_in[6];
  float* out = (float*)d_out;

  // workspace: emb_bf16 51.2MB | kpack 0.5MB | rpack 0.5MB | xkp 83.9MB
  uint16_t* embb  = (uint16_t*)d_ws;
  uint16_t* kpack = embb + (size_t)NV * NE;
  uint16_t* rpack = kpack + (size_t)NE * NU;
  uint16_t* xkp   = rpack + (size_t)NU * NU;

  hipLaunchKernelGGL(emb_to_bf16, dim3(25000), dim3(256), 0, stream, emb, embb);
  hipLaunchKernelGGL(pack_w, dim3(128), dim3(256), 0, stream, kernel_w, kpack);
  hipLaunchKernelGGL(pack_w, dim3(128), dim3(256), 0, stream, rec_w, rpack);
  hipLaunchKernelGGL(proj_gemm, dim3(1280), dim3(256), 0, stream, tokens, embb, kpack, bias, xkp);
  hipLaunchKernelGGL(rnn_rec, dim3(64), dim3(512), 0, stream, xkp, rpack, fcw, fcb, out);
}

// Round 3
// 537.520 us; speedup vs baseline: 1.0545x; 1.0545x over previous
//
#include <hip/hip_runtime.h>
#include <stdint.h>

// Problem constants (B, T, V, E, U)
constexpr int NB = 1024;
constexpr int NT = 80;
constexpr int NV = 50000;
constexpr int NE = 512;
constexpr int NU = 512;

typedef __attribute__((ext_vector_type(8))) __bf16 bf16x8;
typedef __attribute__((ext_vector_type(4))) float f32x4;
typedef __attribute__((ext_vector_type(4))) uint16_t u16x4;
typedef __attribute__((ext_vector_type(4))) float float4v;
typedef __attribute__((ext_vector_type(4))) uint32_t u32x4;

__device__ __forceinline__ uint16_t f2bf(float f) {
  uint32_t u = __builtin_bit_cast(uint32_t, f);
  u += 0x7FFFu + ((u >> 16) & 1u);   // round-to-nearest-even
  return (uint16_t)(u >> 16);
}
__device__ __forceinline__ float bf2f(uint16_t h) {
  uint32_t u = ((uint32_t)h) << 16;
  return __builtin_bit_cast(float, u);
}
__device__ __forceinline__ float tanh_fast(float x) {
  float e = __expf(2.0f * x);
  return 1.0f - 2.0f / (e + 1.0f);
}

// ---------------- prep kernels (unchanged) ----------------

__global__ __launch_bounds__(256) void emb_to_bf16(const float* __restrict__ in,
                                                   uint16_t* __restrict__ out) {
  int i = blockIdx.x * 256 + threadIdx.x;           // 6,400,000 float4s
  float4v v = ((const float4v*)in)[i];
  u16x4 o;
  o.x = f2bf(v.x); o.y = f2bf(v.y); o.z = f2bf(v.z); o.w = f2bf(v.w);
  ((u16x4*)out)[i] = o;
}

// Pack a [K=512][N=512] fp32 weight into MFMA-B-fragment order:
// pack[nt][ks][lane][j] = bf16( W[ks*32 + (lane>>4)*8 + j][nt*16 + (lane&15)] )
__global__ __launch_bounds__(256) void pack_w(const float* __restrict__ w,
                                              uint16_t* __restrict__ out) {
  int idx = blockIdx.x * 256 + threadIdx.x;  // 0..32767 = 32 nt * 16 ks * 64 lanes
  int lane = idx & 63;
  int ks = (idx >> 6) & 15;
  int nt = idx >> 10;
  int n  = nt * 16 + (lane & 15);
  int k0 = ks * 32 + (lane >> 4) * 8;
  uint16_t v[8];
#pragma unroll
  for (int j = 0; j < 8; j++) v[j] = f2bf(w[(size_t)(k0 + j) * NU + n]);
  u16x4* o = (u16x4*)(out + (size_t)idx * 8);
  o[0] = (u16x4){v[0], v[1], v[2], v[3]};
  o[1] = (u16x4){v[4], v[5], v[6], v[7]};
}

// ---------------- projection GEMM (unchanged) -------
__global__ __launch_bounds__(256, 2) void proj_gemm(const int* __restrict__ tokens,
                                                    const uint16_t* __restrict__ embb,
                                                    const uint16_t* __restrict__ kpack,
                                                    const float* __restrict__ bias,
                                                    uint16_t* __restrict__ xkp) {
  int wave = threadIdx.x >> 6;
  int lane = threadIdx.x & 63;
  int ln15 = lane & 15;
  int quad = lane >> 4;
  int m0 = blockIdx.x * 64;      // 1280 blocks: 80 t x 16 b-groups
  int t = m0 >> 10;
  int b0 = m0 & 1023;

  int tok[4];
#pragma unroll
  for (int mt = 0; mt < 4; mt++)
    tok[mt] = tokens[(size_t)(b0 + mt * 16 + ln15) * NT + t];

  float bv[8];
#pragma unroll
  for (int nt = 0; nt < 8; nt++) bv[nt] = bias[wave * 128 + nt * 16 + ln15];

  f32x4 acc[4][8];
#pragma unroll
  for (int mt = 0; mt < 4; mt++)
#pragma unroll
    for (int nt = 0; nt < 8; nt++) acc[mt][nt] = (f32x4){0.f, 0.f, 0.f, 0.f};

  bf16x8 aC[4], aN[4];
#pragma unroll
  for (int mt = 0; mt < 4; mt++) {
    aC[mt] = *(const bf16x8*)(embb + (size_t)tok[mt] * NE + 0 * 32 + quad * 8);
    aN[mt] = *(const bf16x8*)(embb + (size_t)tok[mt] * NE + 1 * 32 + quad * 8);
  }

#pragma unroll 1
  for (int ks = 0; ks < 16; ks++) {
    bf16x8 aF[4];
    int ksn = (ks + 2) & 15;   // wraps harmlessly for ks=14,15
#pragma unroll
    for (int mt = 0; mt < 4; mt++)
      aF[mt] = *(const bf16x8*)(embb + (size_t)tok[mt] * NE + ksn * 32 + quad * 8);
#pragma unroll
    for (int nt = 0; nt < 8; nt++) {
      int ntg = wave * 8 + nt;
      bf16x8 bfr = *(const bf16x8*)(kpack + (((size_t)ntg * 16 + ks) * 64 + lane) * 8);
#pragma unroll
      for (int mt = 0; mt < 4; mt++)
        acc[mt][nt] = __builtin_amdgcn_mfma_f32_16x16x32_bf16(aC[mt], bfr, acc[mt][nt], 0, 0, 0);
    }
#pragma unroll
    for (int mt = 0; mt < 4; mt++) { aC[mt] = aN[mt]; aN[mt] = aF[mt]; }
  }

  // epilogue: C-fragment-order tiles, coalesced 8B/lane stores
#pragma unroll
  for (int mt = 0; mt < 4; mt++) {
    int g = (b0 >> 4) + mt;
#pragma unroll
    for (int nt = 0; nt < 8; nt++) {
      int ntg = wave * 8 + nt;
      size_t tile = ((size_t)t * 64 + g) * 32 + ntg;
      u16x4 o;
      o.x = f2bf(acc[mt][nt][0] + bv[nt]);
      o.y = f2bf(acc[mt][nt][1] + bv[nt]);
      o.z = f2bf(acc[mt][nt][2] + bv[nt]);
      o.w = f2bf(acc[mt][nt][3] + bv[nt]);
      *(u16x4*)(xkp + tile * 256 + (size_t)lane * 4) = o;
    }
  }
}

// ---------------- recurrence: row-split, 12/16 of R persistent ------------
// 64 blocks x 512 threads (8 waves, 2/SIMD, 1 block/CU). Block g owns rows
// g*16..+15, computes ALL 512 cols each step (zero inter-block traffic).
// Per-CU load-path BW ~64 B/clk (~153 GB/s) is the governing ceiling
// (round-2 post-mortem: 512 KB/step remat-stream -> 4.15 us/step matches).
// So: persist 12 of 16 ks-slices of R per block:
//   * ks 0..7  -> registers: bP[8][4] = 128 VGPR/wave, PINNED live with an
//     empty per-iteration asm so the compiler cannot rematerialize them
//     (round-2 failure mode: demand 264 > 256 budget -> remat of all bP).
//     New demand ~244 <= 256.
//   * ks 8..11 -> LDS (128 KB): all 32 nt, lane-linear conflict-free b128.
//   * ks 12..15 -> streamed from L2 each step: 128 KB/block -> ~0.9 us/step
//     floor. 4 laundered base pointers + imm offsets (0..3072) = no VALU.
// h-tile: single 16 KB LDS buffer (A-frag layout, XOR-swizzled slot =
// qw ^ ((row>>1)&3)); 2 barriers/step (reads-done, writes-done).
__global__ __launch_bounds__(512, 2)
void rnn_rec(const uint16_t* __restrict__ xkp,
             const uint16_t* __restrict__ rpack,
             const float* __restrict__ fcw,
             const float* __restrict__ fcb,
             float* __restrict__ out) {
  __shared__ uint16_t hS[8192];              // 16 KB h-tile (single buffer)
  __shared__ uint16_t bL[4 * 32 * 64 * 8];   // 128 KB: B-frags ks 8..11, all nt

  const int g = blockIdx.x;
  const int wave = threadIdx.x >> 6, lane = threadIdx.x & 63;
  const int ln15 = lane & 15, quad = lane >> 4;
  const int ntg0 = wave * 4;                    // first owned n-tile (of 32)
  const int aswz = quad ^ ((ln15 >> 1) & 3);    // swizzled 16B-slot for A-reads

  // persistent B-frags ks 0..7 (128 VGPR)
  bf16x8 bP[8][4];
#pragma unroll
  for (int ks = 0; ks < 8; ks++)
#pragma unroll
    for (int n = 0; n < 4; n++)
      bP[ks][n] = *(const bf16x8*)(rpack + (((size_t)(ntg0 + n) * 16 + ks) * 64 + lane) * 8);

  // fill bL: 8192 frags (4 ksl x 32 nt x 64 lanes), 16 B each
#pragma unroll
  for (int i = 0; i < 16; i++) {
    int f = i * 512 + threadIdx.x;
    int l = f & 63, nt = (f >> 6) & 31, ksl = f >> 11;
    *(u32x4*)(bL + (size_t)f * 8) =
        *(const u32x4*)(rpack + (((size_t)nt * 16 + 8 + ksl) * 64 + l) * 8);
  }

  // h(0) = 0
  {
    u32x4 z = (u32x4){0u, 0u, 0u, 0u};
    ((u32x4*)hS)[threadIdx.x] = z;
    ((u32x4*)hS)[512 + threadIdx.x] = z;
  }

  // xk(0) prefetch
  u16x4 xc[4];
#pragma unroll
  for (int n = 0; n < 4; n++)
    xc[n] = *(const u16x4*)(xkp + (((size_t)0 * 64 + g) * 32 + ntg0 + n) * 256 + (size_t)lane * 4);

  // stream base pointers (ks=12 start) per owned nt; ks offsets are imm
  const uint16_t* sp0 = rpack + (((size_t)(ntg0 + 0) * 16 + 12) * 64 + lane) * 8;
  const uint16_t* sp1 = rpack + (((size_t)(ntg0 + 1) * 16 + 12) * 64 + lane) * 8;
  const uint16_t* sp2 = rpack + (((size_t)(ntg0 + 2) * 16 + 12) * 64 + lane) * 8;
  const uint16_t* sp3 = rpack + (((size_t)(ntg0 + 3) * 16 + 12) * 64 + lane) * 8;

  __syncthreads();

#pragma unroll 1
  for (int t = 0; t < NT; ++t) {
    // pin persistent B-frags (forbid remat), launder stream ptrs (forbid hoist)
#pragma unroll
    for (int ks = 0; ks < 8; ks++)
#pragma unroll
      for (int n = 0; n < 4; n++)
        asm volatile("" : "+v"(bP[ks][n]));
    asm volatile("" : "+v"(sp0), "+v"(sp1), "+v"(sp2), "+v"(sp3));

    const uint16_t* sp[4] = {sp0, sp1, sp2, sp3};

    // issue stream batch 0: ks 12,13 (8 x b128, offsets 0 / 1024 B)
    bf16x8 s0[2][4];
#pragma unroll
    for (int k = 0; k < 2; k++)
#pragma unroll
      for (int n = 0; n < 4; n++)
        s0[k][n] = *(const bf16x8*)(sp[n] + (size_t)k * 512);

    // prefetch xk(t+1)
    u16x4 xn[4];
    {
      int tn = (t + 1 < NT) ? t + 1 : t;
#pragma unroll
      for (int n = 0; n < 4; n++)
        xn[n] = *(const u16x4*)(xkp + (((size_t)tn * 64 + g) * 32 + ntg0 + n) * 256 + (size_t)lane * 4);
    }

    f32x4 acc[4];
#pragma unroll
    for (int n = 0; n < 4; n++) acc[n] = (f32x4){0.f, 0.f, 0.f, 0.f};

    // phase 1: ks 0..7 from registers (covers batch-0 L2 latency)
#pragma unroll
    for (int ks = 0; ks < 8; ks++) {
      bf16x8 a = *(const bf16x8*)(hS + (size_t)ks * 512 + ln15 * 32 + aswz * 8);
#pragma unroll
      for (int n = 0; n < 4; n++)
        acc[n] = __builtin_amdgcn_mfma_f32_16x16x32_bf16(a, bP[ks][n], acc[n], 0, 0, 0);
    }

    // issue stream batch 1: ks 14,15 (offsets 2048 / 3072 B)
    bf16x8 s1[2][4];
#pragma unroll
    for (int k = 0; k < 2; k++)
#pragma unroll
      for (int n = 0; n < 4; n++)
        s1[k][n] = *(const bf16x8*)(sp[n] + (size_t)(2 + k) * 512);

    // phase 2: ks 8..11 from LDS
#pragma unroll
    for (int ksl = 0; ksl < 4; ksl++) {
      bf16x8 a = *(const bf16x8*)(hS + (size_t)(8 + ksl) * 512 + ln15 * 32 + aswz * 8);
#pragma unroll
      for (int n = 0; n < 4; n++) {
        bf16x8 bq = *(const bf16x8*)(bL + (((size_t)ksl * 32 + ntg0 + n) * 64 + lane) * 8);
        acc[n] = __builtin_amdgcn_mfma_f32_16x16x32_bf16(a, bq, acc[n], 0, 0, 0);
      }
    }

    // phase 3: consume streamed ks 12,13 then 14,15
#pragma unroll
    for (int k = 0; k < 2; k++) {
      bf16x8 a = *(const bf16x8*)(hS + (size_t)(12 + k) * 512 + ln15 * 32 + aswz * 8);
#pragma unroll
      for (int n = 0; n < 4; n++)
        acc[n] = __builtin_amdgcn_mfma_f32_16x16x32_bf16(a, s0[k][n], acc[n], 0, 0, 0);
    }
#pragma unroll
    for (int k = 0; k < 2; k++) {
      bf16x8 a = *(const bf16x8*)(hS + (size_t)(14 + k) * 512 + ln15 * 32 + aswz * 8);
#pragma unroll
      for (int n = 0; n < 4; n++)
        acc[n] = __builtin_amdgcn_mfma_f32_16x16x32_bf16(a, s1[k][n], acc[n], 0, 0, 0);
    }

    // tanh
    uint16_t hv[4][4];
#pragma unroll
    for (int n = 0; n < 4; n++)
#pragma unroll
      for (int r = 0; r < 4; r++)
        hv[n][r] = f2bf(tanh_fast(acc[n][r] + bf2f(xc[n][r])));
#pragma unroll
    for (int n = 0; n < 4; n++) xc[n] = xn[n];

    __syncthreads();   // all hS reads of step t done

    // repack own 64 cols into hS (swizzled scatter)
#pragma unroll
    for (int n = 0; n < 4; n++) {
      int col = wave * 64 + n * 16 + ln15;
      int ksR = col >> 5;
      int qw = (col >> 3) & 3;
      int j = col & 7;
#pragma unroll
      for (int r = 0; r < 4; r++) {
        int row = quad * 4 + r;
        hS[(size_t)ksR * 512 + row * 32 + ((qw ^ ((row >> 1) & 3)) << 3) + j] = hv[n][r];
      }
    }
    __syncthreads();   // h(t+1) complete
  }

  // final FC + sigmoid: each wave does 2 rows (8 waves x 2 = 16)
  {
#pragma unroll
    for (int rr = 0; rr < 2; rr++) {
      int row = wave * 2 + rr;
      // cols lane*8..+7: ks = lane>>2, logical qw = lane&3 -> swizzled slot
      int slot = (lane & 3) ^ ((row >> 1) & 3);
      const uint16_t* hr = hS + (size_t)(lane >> 2) * 512 + row * 32 + slot * 8;
      float p = 0.f;
#pragma unroll
      for (int j = 0; j < 8; j++) p += bf2f(hr[j]) * fcw[lane * 8 + j];
#pragma unroll
      for (int off = 32; off; off >>= 1) p += __shfl_down(p, off);
      if (lane == 0) {
        float logit = p + fcb[0];
        out[g * 16 + row] = 1.0f / (1.0f + __expf(-logit));
      }
    }
  }
}

// ---------------- launcher ----------------
extern "C" void kernel_launch(void* const* d_in, const int* in_sizes, int n_in,
                              void* d_out, int out_size, void* d_ws, size_t ws_size,
                              hipStream_t stream) {
  const int* tokens   = (const int*)d_in[0];
  const float* emb    = (const float*)d_in[1];
  const float* kernel_w = (const float*)d_in[2];
  const float* rec_w  = (const float*)d_in[3];
  const float* bias   = (const float*)d_in[4];
  const float* fcw    = (const float*)d_in[5];
  const float* fcb    = (const float*)d_in[6];
  float* out = (float*)d_out;

  // workspace: emb_bf16 51.2MB | kpack 0.5MB | rpack 0.5MB | xkp 83.9MB
  uint16_t* embb  = (uint16_t*)d_ws;
  uint16_t* kpack = embb + (size_t)NV * NE;
  uint16_t* rpack = kpack + (size_t)NE * NU;
  uint16_t* xkp   = rpack + (size_t)NU * NU;

  hipLaunchKernelGGL(emb_to_bf16, dim3(25000), dim3(256), 0, stream, emb, embb);
  hipLaunchKernelGGL(pack_w, dim3(128), dim3(256), 0, stream, kernel_w, kpack);
  hipLaunchKernelGGL(pack_w, dim3(128), dim3(256), 0, stream, rec_w, rpack);
  hipLaunchKernelGGL(proj_gemm, dim3(1280), dim3(256), 0, stream, tokens, embb, kpack, bias, xkp);
  hipLaunchKernelGGL(rnn_rec, dim3(64), dim3(512), 0, stream, xkp, rpack, fcw, fcb, out);
}

// Round 4
// 495.624 us; speedup vs baseline: 1.1436x; 1.0845x over previous
//
#include <hip/hip_runtime.h>
#include <stdint.h>

// Problem constants (B, T, V, E, U)
constexpr int NB = 1024;
constexpr int NT = 80;
constexpr int NV = 50000;
constexpr int NE = 512;
constexpr int NU = 512;

typedef __attribute__((ext_vector_type(8))) __bf16 bf16x8;
typedef __attribute__((ext_vector_type(4))) float f32x4;
typedef __attribute__((ext_vector_type(4))) uint16_t u16x4;
typedef __attribute__((ext_vector_type(4))) float float4v;
typedef __attribute__((ext_vector_type(4))) uint32_t u32x4;

__device__ __forceinline__ uint16_t f2bf(float f) {
  uint32_t u = __builtin_bit_cast(uint32_t, f);
  u += 0x7FFFu + ((u >> 16) & 1u);   // round-to-nearest-even
  return (uint16_t)(u >> 16);
}
__device__ __forceinline__ float bf2f(uint16_t h) {
  uint32_t u = ((uint32_t)h) << 16;
  return __builtin_bit_cast(float, u);
}
__device__ __forceinline__ float tanh_fast(float x) {
  float e = __expf(2.0f * x);
  return 1.0f - 2.0f / (e + 1.0f);
}

// ---------------- prep kernels (unchanged) ----------------

__global__ __launch_bounds__(256) void emb_to_bf16(const float* __restrict__ in,
                                                   uint16_t* __restrict__ out) {
  int i = blockIdx.x * 256 + threadIdx.x;           // 6,400,000 float4s
  float4v v = ((const float4v*)in)[i];
  u16x4 o;
  o.x = f2bf(v.x); o.y = f2bf(v.y); o.z = f2bf(v.z); o.w = f2bf(v.w);
  ((u16x4*)out)[i] = o;
}

// Pack a [K=512][N=512] fp32 weight into MFMA-B-fragment order:
// pack[nt][ks][lane][j] = bf16( W[ks*32 + (lane>>4)*8 + j][nt*16 + (lane&15)] )
__global__ __launch_bounds__(256) void pack_w(const float* __restrict__ w,
                                              uint16_t* __restrict__ out) {
  int idx = blockIdx.x * 256 + threadIdx.x;  // 0..32767 = 32 nt * 16 ks * 64 lanes
  int lane = idx & 63;
  int ks = (idx >> 6) & 15;
  int nt = idx >> 10;
  int n  = nt * 16 + (lane & 15);
  int k0 = ks * 32 + (lane >> 4) * 8;
  uint16_t v[8];
#pragma unroll
  for (int j = 0; j < 8; j++) v[j] = f2bf(w[(size_t)(k0 + j) * NU + n]);
  u16x4* o = (u16x4*)(out + (size_t)idx * 8);
  o[0] = (u16x4){v[0], v[1], v[2], v[3]};
  o[1] = (u16x4){v[4], v[5], v[6], v[7]};
}

// ---------------- projection GEMM (unchanged) -------
__global__ __launch_bounds__(256, 2) void proj_gemm(const int* __restrict__ tokens,
                                                    const uint16_t* __restrict__ embb,
                                                    const uint16_t* __restrict__ kpack,
                                                    const float* __restrict__ bias,
                                                    uint16_t* __restrict__ xkp) {
  int wave = threadIdx.x >> 6;
  int lane = threadIdx.x & 63;
  int ln15 = lane & 15;
  int quad = lane >> 4;
  int m0 = blockIdx.x * 64;      // 1280 blocks: 80 t x 16 b-groups
  int t = m0 >> 10;
  int b0 = m0 & 1023;

  int tok[4];
#pragma unroll
  for (int mt = 0; mt < 4; mt++)
    tok[mt] = tokens[(size_t)(b0 + mt * 16 + ln15) * NT + t];

  float bv[8];
#pragma unroll
  for (int nt = 0; nt < 8; nt++) bv[nt] = bias[wave * 128 + nt * 16 + ln15];

  f32x4 acc[4][8];
#pragma unroll
  for (int mt = 0; mt < 4; mt++)
#pragma unroll
    for (int nt = 0; nt < 8; nt++) acc[mt][nt] = (f32x4){0.f, 0.f, 0.f, 0.f};

  bf16x8 aC[4], aN[4];
#pragma unroll
  for (int mt = 0; mt < 4; mt++) {
    aC[mt] = *(const bf16x8*)(embb + (size_t)tok[mt] * NE + 0 * 32 + quad * 8);
    aN[mt] = *(const bf16x8*)(embb + (size_t)tok[mt] * NE + 1 * 32 + quad * 8);
  }

#pragma unroll 1
  for (int ks = 0; ks < 16; ks++) {
    bf16x8 aF[4];
    int ksn = (ks + 2) & 15;   // wraps harmlessly for ks=14,15
#pragma unroll
    for (int mt = 0; mt < 4; mt++)
      aF[mt] = *(const bf16x8*)(embb + (size_t)tok[mt] * NE + ksn * 32 + quad * 8);
#pragma unroll
    for (int nt = 0; nt < 8; nt++) {
      int ntg = wave * 8 + nt;
      bf16x8 bfr = *(const bf16x8*)(kpack + (((size_t)ntg * 16 + ks) * 64 + lane) * 8);
#pragma unroll
      for (int mt = 0; mt < 4; mt++)
        acc[mt][nt] = __builtin_amdgcn_mfma_f32_16x16x32_bf16(aC[mt], bfr, acc[mt][nt], 0, 0, 0);
    }
#pragma unroll
    for (int mt = 0; mt < 4; mt++) { aC[mt] = aN[mt]; aN[mt] = aF[mt]; }
  }

  // epilogue: C-fragment-order tiles, coalesced 8B/lane stores
#pragma unroll
  for (int mt = 0; mt < 4; mt++) {
    int g = (b0 >> 4) + mt;
#pragma unroll
    for (int nt = 0; nt < 8; nt++) {
      int ntg = wave * 8 + nt;
      size_t tile = ((size_t)t * 64 + g) * 32 + ntg;
      u16x4 o;
      o.x = f2bf(acc[mt][nt][0] + bv[nt]);
      o.y = f2bf(acc[mt][nt][1] + bv[nt]);
      o.z = f2bf(acc[mt][nt][2] + bv[nt]);
      o.w = f2bf(acc[mt][nt][3] + bv[nt]);
      *(u16x4*)(xkp + tile * 256 + (size_t)lane * 4) = o;
    }
  }
}

// ---------------- recurrence: row-split, 12/16 R persistent, no spill -----
// 64 blocks x 512 threads (8 waves, 2/SIMD, 1 block/CU). Block g owns rows
// g*16..+15, computes ALL 512 cols each step. Round-3 failure: in-loop pins
// forced bP liveness but demand ~250+ > 256 -> allocator SPILLED bP to
// scratch (VGPR_Count=128; scratch is LLC-resident so invisible in
// FETCH/WRITE; 512 KB/CU/step scratch traffic == measured 3.78us/step).
// Round-4 fix = register diet to ~214 live:
//   * bP pinned ONCE pre-loop (asm output can't be remat'd; no per-iter
//     redefinition)
//   * stream ks12..15 as four 1-ks batches through TWO 16-reg buffers
//   * no xn prefetch regs: xk(t) loaded at top of step t, consumed ~600cy
//     later at tanh (fully hidden); xkp pointer bumped +1MB/step
// h-tile: single 16 KB LDS buffer (A-frag layout, XOR-swizzled slot =
// qw ^ ((row>>1)&3)); 2 barriers/step. bL: 128 KB LDS, ks 8..11, all nt.
__global__ __launch_bounds__(512, 2)
void rnn_rec(const uint16_t* __restrict__ xkp,
             const uint16_t* __restrict__ rpack,
             const float* __restrict__ fcw,
             const float* __restrict__ fcb,
             float* __restrict__ out) {
  __shared__ uint16_t hS[8192];              // 16 KB h-tile (single buffer)
  __shared__ uint16_t bL[4 * 32 * 64 * 8];   // 128 KB: B-frags ks 8..11, all nt

  const int g = blockIdx.x;
  const int wave = threadIdx.x >> 6, lane = threadIdx.x & 63;
  const int ln15 = lane & 15, quad = lane >> 4;
  const int ntg0 = wave * 4;                    // first owned n-tile (of 32)
  const int aswz = quad ^ ((ln15 >> 1) & 3);    // swizzled 16B-slot for A-reads

  // persistent B-frags ks 0..7 (128 VGPR)
  bf16x8 bP[8][4];
#pragma unroll
  for (int ks = 0; ks < 8; ks++)
#pragma unroll
    for (int n = 0; n < 4; n++)
      bP[ks][n] = *(const bf16x8*)(rpack + (((size_t)(ntg0 + n) * 16 + ks) * 64 + lane) * 8);
  // pin ONCE: values become opaque asm outputs -> remat impossible; with
  // steady-state demand ~214 < 256 the allocator has no reason to spill.
#pragma unroll
  for (int ks = 0; ks < 8; ks++)
    asm volatile("" : "+v"(bP[ks][0]), "+v"(bP[ks][1]), "+v"(bP[ks][2]), "+v"(bP[ks][3]));

  // fill bL: 8192 frags (4 ksl x 32 nt x 64 lanes), 16 B each
#pragma unroll
  for (int i = 0; i < 16; i++) {
    int f = i * 512 + threadIdx.x;
    int l = f & 63, nt = (f >> 6) & 31, ksl = f >> 11;
    *(u32x4*)(bL + (size_t)f * 8) =
        *(const u32x4*)(rpack + (((size_t)nt * 16 + 8 + ksl) * 64 + l) * 8);
  }

  // h(0) = 0
  {
    u32x4 z = (u32x4){0u, 0u, 0u, 0u};
    ((u32x4*)hS)[threadIdx.x] = z;
    ((u32x4*)hS)[512 + threadIdx.x] = z;
  }

  // stream base pointers (ks=12..15 at imm offsets 0/1024/2048/3072 B)
  const uint16_t* sp0 = rpack + (((size_t)(ntg0 + 0) * 16 + 12) * 64 + lane) * 8;
  const uint16_t* sp1 = rpack + (((size_t)(ntg0 + 1) * 16 + 12) * 64 + lane) * 8;
  const uint16_t* sp2 = rpack + (((size_t)(ntg0 + 2) * 16 + 12) * 64 + lane) * 8;
  const uint16_t* sp3 = rpack + (((size_t)(ntg0 + 3) * 16 + 12) * 64 + lane) * 8;

  // xk pointer for step t (advanced +1MB per step); nt offsets are imm 512B
  const uint16_t* xp = xkp + ((size_t)g * 32 + ntg0) * 256 + (size_t)lane * 4;

  __syncthreads();

#pragma unroll 1
  for (int t = 0; t < NT; ++t) {
    // launder stream ptrs each iter: forbids hoisting the loop-invariant
    // rpack loads out of the loop (which would blow the register budget)
    asm volatile("" : "+v"(sp0), "+v"(sp1), "+v"(sp2), "+v"(sp3));

    // batch A = ks12, batch B = ks13 (16 regs each)
    bf16x8 sA[4], sB[4];
    sA[0] = *(const bf16x8*)(sp0 + 0 * 512);
    sA[1] = *(const bf16x8*)(sp1 + 0 * 512);
    sA[2] = *(const bf16x8*)(sp2 + 0 * 512);
    sA[3] = *(const bf16x8*)(sp3 + 0 * 512);
    sB[0] = *(const bf16x8*)(sp0 + 1 * 512);
    sB[1] = *(const bf16x8*)(sp1 + 1 * 512);
    sB[2] = *(const bf16x8*)(sp2 + 1 * 512);
    sB[3] = *(const bf16x8*)(sp3 + 1 * 512);

    // xk(t): consumed ~600cy later at the tanh -> latency fully hidden
    u16x4 xc[4];
#pragma unroll
    for (int n = 0; n < 4; n++)
      xc[n] = *(const u16x4*)(xp + n * 256);

    f32x4 acc[4];
#pragma unroll
    for (int n = 0; n < 4; n++) acc[n] = (f32x4){0.f, 0.f, 0.f, 0.f};

    // phase 1: ks 0..7 from registers (covers sA/sB L2 latency)
#pragma unroll
    for (int ks = 0; ks < 8; ks++) {
      bf16x8 a = *(const bf16x8*)(hS + (size_t)ks * 512 + ln15 * 32 + aswz * 8);
#pragma unroll
      for (int n = 0; n < 4; n++)
        acc[n] = __builtin_amdgcn_mfma_f32_16x16x32_bf16(a, bP[ks][n], acc[n], 0, 0, 0);
    }

    // consume ks12 (sA); refill sA with ks14
    {
      bf16x8 a = *(const bf16x8*)(hS + (size_t)12 * 512 + ln15 * 32 + aswz * 8);
#pragma unroll
      for (int n = 0; n < 4; n++)
        acc[n] = __builtin_amdgcn_mfma_f32_16x16x32_bf16(a, sA[n], acc[n], 0, 0, 0);
    }
    sA[0] = *(const bf16x8*)(sp0 + 2 * 512);
    sA[1] = *(const bf16x8*)(sp1 + 2 * 512);
    sA[2] = *(const bf16x8*)(sp2 + 2 * 512);
    sA[3] = *(const bf16x8*)(sp3 + 2 * 512);

    // phase 2a: ks 8,9 from LDS (covers sA=ks14 latency)
#pragma unroll
    for (int ksl = 0; ksl < 2; ksl++) {
      bf16x8 a = *(const bf16x8*)(hS + (size_t)(8 + ksl) * 512 + ln15 * 32 + aswz * 8);
#pragma unroll
      for (int n = 0; n < 4; n++) {
        bf16x8 bq = *(const bf16x8*)(bL + (((size_t)ksl * 32 + ntg0 + n) * 64 + lane) * 8);
        acc[n] = __builtin_amdgcn_mfma_f32_16x16x32_bf16(a, bq, acc[n], 0, 0, 0);
      }
    }

    // consume ks13 (sB); refill sB with ks15
    {
      bf16x8 a = *(const bf16x8*)(hS + (size_t)13 * 512 + ln15 * 32 + aswz * 8);
#pragma unroll
      for (int n = 0; n < 4; n++)
        acc[n] = __builtin_amdgcn_mfma_f32_16x16x32_bf16(a, sB[n], acc[n], 0, 0, 0);
    }
    sB[0] = *(const bf16x8*)(sp0 + 3 * 512);
    sB[1] = *(const bf16x8*)(sp1 + 3 * 512);
    sB[2] = *(const bf16x8*)(sp2 + 3 * 512);
    sB[3] = *(const bf16x8*)(sp3 + 3 * 512);

    // phase 2b: ks 10,11 from LDS (covers sB=ks15 latency)
#pragma unroll
    for (int ksl = 2; ksl < 4; ksl++) {
      bf16x8 a = *(const bf16x8*)(hS + (size_t)(8 + ksl) * 512 + ln15 * 32 + aswz * 8);
#pragma unroll
      for (int n = 0; n < 4; n++) {
        bf16x8 bq = *(const bf16x8*)(bL + (((size_t)ksl * 32 + ntg0 + n) * 64 + lane) * 8);
        acc[n] = __builtin_amdgcn_mfma_f32_16x16x32_bf16(a, bq, acc[n], 0, 0, 0);
      }
    }

    // consume ks14 (sA), ks15 (sB)
    {
      bf16x8 a = *(const bf16x8*)(hS + (size_t)14 * 512 + ln15 * 32 + aswz * 8);
#pragma unroll
      for (int n = 0; n < 4; n++)
        acc[n] = __builtin_amdgcn_mfma_f32_16x16x32_bf16(a, sA[n], acc[n], 0, 0, 0);
    }
    {
      bf16x8 a = *(const bf16x8*)(hS + (size_t)15 * 512 + ln15 * 32 + aswz * 8);
#pragma unroll
      for (int n = 0; n < 4; n++)
        acc[n] = __builtin_amdgcn_mfma_f32_16x16x32_bf16(a, sB[n], acc[n], 0, 0, 0);
    }

    // tanh
    uint16_t hv[4][4];
#pragma unroll
    for (int n = 0; n < 4; n++)
#pragma unroll
      for (int r = 0; r < 4; r++)
        hv[n][r] = f2bf(tanh_fast(acc[n][r] + bf2f(xc[n][r])));

    xp += (size_t)64 * 32 * 256;   // advance to step t+1 (+1 MB)

    __syncthreads();   // all hS reads of step t done

    // repack own 64 cols into hS (swizzled scatter)
#pragma unroll
    for (int n = 0; n < 4; n++) {
      int col = wave * 64 + n * 16 + ln15;
      int ksR = col >> 5;
      int qw = (col >> 3) & 3;
      int j = col & 7;
#pragma unroll
      for (int r = 0; r < 4; r++) {
        int row = quad * 4 + r;
        hS[(size_t)ksR * 512 + row * 32 + ((qw ^ ((row >> 1) & 3)) << 3) + j] = hv[n][r];
      }
    }
    __syncthreads();   // h(t+1) complete
  }

  // final FC + sigmoid: each wave does 2 rows (8 waves x 2 = 16)
  {
#pragma unroll
    for (int rr = 0; rr < 2; rr++) {
      int row = wave * 2 + rr;
      // cols lane*8..+7: ks = lane>>2, logical qw = lane&3 -> swizzled slot
      int slot = (lane & 3) ^ ((row >> 1) & 3);
      const uint16_t* hr = hS + (size_t)(lane >> 2) * 512 + row * 32 + slot * 8;
      float p = 0.f;
#pragma unroll
      for (int j = 0; j < 8; j++) p += bf2f(hr[j]) * fcw[lane * 8 + j];
#pragma unroll
      for (int off = 32; off; off >>= 1) p += __shfl_down(p, off);
      if (lane == 0) {
        float logit = p + fcb[0];
        out[g * 16 + row] = 1.0f / (1.0f + __expf(-logit));
      }
    }
  }
}

// ---------------- launcher ----------------
extern "C" void kernel_launch(void* const* d_in, const int* in_sizes, int n_in,
                              void* d_out, int out_size, void* d_ws, size_t ws_size,
                              hipStream_t stream) {
  const int* tokens   = (const int*)d_in[0];
  const float* emb    = (const float*)d_in[1];
  const float* kernel_w = (const float*)d_in[2];
  const float* rec_w  = (const float*)d_in[3];
  const float* bias   = (const float*)d_in[4];
  const float* fcw    = (const float*)d_in[5];
  const float* fcb    = (const float*)d_in[6];
  float* out = (float*)d_out;

  // workspace: emb_bf16 51.2MB | kpack 0.5MB | rpack 0.5MB | xkp 83.9MB
  uint16_t* embb  = (uint16_t*)d_ws;
  uint16_t* kpack = embb + (size_t)NV * NE;
  uint16_t* rpack = kpack + (size_t)NE * NU;
  uint16_t* xkp   = rpack + (size_t)NU * NU;

  hipLaunchKernelGGL(emb_to_bf16, dim3(25000), dim3(256), 0, stream, emb, embb);
  hipLaunchKernelGGL(pack_w, dim3(128), dim3(256), 0, stream, kernel_w, kpack);
  hipLaunchKernelGGL(pack_w, dim3(128), dim3(256), 0, stream, rec_w, rpack);
  hipLaunchKernelGGL(proj_gemm, dim3(1280), dim3(256), 0, stream, tokens, embb, kpack, bias, xkp);
  hipLaunchKernelGGL(rnn_rec, dim3(64), dim3(512), 0, stream, xkp, rpack, fcw, fcb, out);
}